// Round 2
// baseline (24278.720 us; speedup 1.0000x reference)
//
#include <hip/hip_runtime.h>

#define NUSERS 100000
#define NITEMS 200000
#define NNODES 300000
#define DIM 64
#define NEDGES 9600000

// ---------------------------------------------------------------------------
// concat: e0 = [user_emb; item_emb], vectorized float4
// ---------------------------------------------------------------------------
__global__ void concat_kernel(const float4* __restrict__ u,
                              const float4* __restrict__ it,
                              float4* __restrict__ e0) {
    int i = blockIdx.x * blockDim.x + threadIdx.x;
    const int nu4  = NUSERS * (DIM / 4);   // 1,600,000
    const int tot4 = NNODES * (DIM / 4);   // 4,800,000
    if (i < tot4) {
        e0[i] = (i < nu4) ? u[i] : it[i - nu4];
    }
}

// ---------------------------------------------------------------------------
// SpMM via atomics: one thread handles one (edge, 4-dim quarter).
// Lanes 0..15 of each 16-thread group share an edge -> the 16 float4 gathers
// cover the full contiguous 256B source row (coalesced), likewise the atomics
// on the destination row.
// ---------------------------------------------------------------------------
__global__ void spmm_kernel(const int* __restrict__ row,
                            const int* __restrict__ col,
                            const float* __restrict__ val,
                            const float* __restrict__ x,
                            float* __restrict__ y) {
    long long tid = (long long)blockIdx.x * blockDim.x + threadIdx.x;
    if (tid >= (long long)NEDGES * 16) return;
    int e = (int)(tid >> 4);
    int q = (int)(tid & 15);
    int r = row[e];
    int c = col[e];
    float v = val[e];
    float4 xv = ((const float4*)x)[(size_t)c * 16 + q];
    float* yp = y + (size_t)r * 64 + q * 4;
    atomicAdd(yp + 0, v * xv.x);
    atomicAdd(yp + 1, v * xv.y);
    atomicAdd(yp + 2, v * xv.z);
    atomicAdd(yp + 3, v * xv.w);
}

// ---------------------------------------------------------------------------
// finalize: mean over the 4 stored embeddings, split users/items
// ---------------------------------------------------------------------------
__global__ void finalize_kernel(const float4* __restrict__ e0,
                                const float4* __restrict__ e1,
                                const float4* __restrict__ e2,
                                const float4* __restrict__ e3,
                                float4* __restrict__ users,
                                float4* __restrict__ items) {
    int i = blockIdx.x * blockDim.x + threadIdx.x;
    const int tot4 = NNODES * (DIM / 4);
    if (i >= tot4) return;
    float4 a = e0[i], b = e1[i], c = e2[i], d = e3[i];
    float4 m;
    m.x = (a.x + b.x + c.x + d.x) * 0.25f;
    m.y = (a.y + b.y + c.y + d.y) * 0.25f;
    m.z = (a.z + b.z + c.z + d.z) * 0.25f;
    m.w = (a.w + b.w + c.w + d.w) * 0.25f;
    const int nu4 = NUSERS * (DIM / 4);
    if (i < nu4) users[i] = m;
    else         items[i - nu4] = m;
}

extern "C" void kernel_launch(void* const* d_in, const int* in_sizes, int n_in,
                              void* d_out, int out_size, void* d_ws, size_t ws_size,
                              hipStream_t stream) {
    const float* user_emb = (const float*)d_in[0];
    const float* item_emb = (const float*)d_in[1];
    const int*   adj_row  = (const int*)d_in[2];
    const int*   adj_col  = (const int*)d_in[3];
    const float* adj_val  = (const float*)d_in[4];

    float* out   = (float*)d_out;
    float* users = out;                                   // 100000*64
    float* items = out + (size_t)NUSERS * DIM;            // 200000*64
    float* e0    = out + (size_t)NNODES * DIM;            // embs[0]
    float* e1    = e0 + (size_t)NNODES * DIM;             // embs[1]
    float* e2    = e1 + (size_t)NNODES * DIM;             // embs[2]
    float* e3    = e2 + (size_t)NNODES * DIM;             // embs[3]

    const int tot4 = NNODES * (DIM / 4);                  // 4.8M float4
    const int cblk = 256;

    // e0 = concat(user_emb, item_emb)
    concat_kernel<<<(tot4 + cblk - 1) / cblk, cblk, 0, stream>>>(
        (const float4*)user_emb, (const float4*)item_emb, (float4*)e0);

    // zero the three accumulator layers (d_out is poisoned to 0xAA)
    hipMemsetAsync(e1, 0, (size_t)3 * NNODES * DIM * sizeof(float), stream);

    // 3 SpMM layers
    const long long spmm_threads = (long long)NEDGES * 16;   // 153.6M
    const int sblk = 256;
    const int sgrid = (int)((spmm_threads + sblk - 1) / sblk);
    spmm_kernel<<<sgrid, sblk, 0, stream>>>(adj_row, adj_col, adj_val, e0, e1);
    spmm_kernel<<<sgrid, sblk, 0, stream>>>(adj_row, adj_col, adj_val, e1, e2);
    spmm_kernel<<<sgrid, sblk, 0, stream>>>(adj_row, adj_col, adj_val, e2, e3);

    // mean + split
    finalize_kernel<<<(tot4 + cblk - 1) / cblk, cblk, 0, stream>>>(
        (const float4*)e0, (const float4*)e1, (const float4*)e2, (const float4*)e3,
        (float4*)users, (float4*)items);
}

// Round 3
// 2196.580 us; speedup vs baseline: 11.0530x; 11.0530x over previous
//
#include <hip/hip_runtime.h>

#define NUSERS 100000
#define NITEMS 200000
#define NNODES 300000
#define DIM 64
#define NEDGES 9600000
#define SCAN_BLK 1024
#define NBLK1 ((NNODES + SCAN_BLK - 1) / SCAN_BLK)   // 293

static_assert(NBLK1 <= 512, "scan2 assumes block sums fit one 512-thread block");

// ---------------------------------------------------------------------------
// concat: e0 = [user_emb; item_emb], float4
// ---------------------------------------------------------------------------
__global__ void concat_kernel(const float4* __restrict__ u,
                              const float4* __restrict__ it,
                              float4* __restrict__ e0) {
    int i = blockIdx.x * blockDim.x + threadIdx.x;
    const int nu4  = NUSERS * (DIM / 4);
    const int tot4 = NNODES * (DIM / 4);
    if (i < tot4) e0[i] = (i < nu4) ? u[i] : it[i - nu4];
}

// ---------------------------------------------------------------------------
// CSR build: histogram -> scan -> scatter
// ---------------------------------------------------------------------------
__global__ void hist_kernel(const int* __restrict__ row, int* __restrict__ cnt) {
    int e = blockIdx.x * blockDim.x + threadIdx.x;
    if (e < NEDGES) atomicAdd(&cnt[row[e]], 1);
}

// per-block exclusive scan of cnt -> excl (local), block total -> blockSums
__global__ void scan1_kernel(const int* __restrict__ cnt,
                             int* __restrict__ excl,
                             int* __restrict__ blockSums) {
    __shared__ int sm[SCAN_BLK];
    int t = threadIdx.x;
    int g = blockIdx.x * SCAN_BLK + t;
    int v = (g < NNODES) ? cnt[g] : 0;
    sm[t] = v;
    __syncthreads();
    for (int off = 1; off < SCAN_BLK; off <<= 1) {
        int tmp = (t >= off) ? sm[t - off] : 0;
        __syncthreads();
        sm[t] += tmp;
        __syncthreads();
    }
    if (g < NNODES) excl[g] = sm[t] - v;                 // exclusive
    if (t == SCAN_BLK - 1) blockSums[blockIdx.x] = sm[t];
}

// single-block inclusive scan of blockSums
__global__ void scan2_kernel(int* __restrict__ blockSums) {
    __shared__ int sm[512];
    int t = threadIdx.x;
    sm[t] = (t < NBLK1) ? blockSums[t] : 0;
    __syncthreads();
    for (int off = 1; off < 512; off <<= 1) {
        int tmp = (t >= off) ? sm[t - off] : 0;
        __syncthreads();
        sm[t] += tmp;
        __syncthreads();
    }
    if (t < NBLK1) blockSums[t] = sm[t];                 // inclusive
}

// add block offsets; write final ptr and cursor copy
__global__ void scan3_kernel(int* __restrict__ ptr, int* __restrict__ cursor,
                             const int* __restrict__ blockIncl) {
    int b = blockIdx.x;
    int g = b * SCAN_BLK + threadIdx.x;
    int off = (b > 0) ? blockIncl[b - 1] : 0;
    if (g < NNODES) {
        int p = ptr[g] + off;
        ptr[g] = p;
        cursor[g] = p;
    }
    if (g == 0) { ptr[NNODES] = NEDGES; cursor[NNODES] = NEDGES; }
}

__global__ void scatter_kernel(const int* __restrict__ row,
                               const int* __restrict__ col,
                               const float* __restrict__ val,
                               int* __restrict__ cursor,
                               int* __restrict__ cols_s,
                               float* __restrict__ vals_s) {
    int e = blockIdx.x * blockDim.x + threadIdx.x;
    if (e >= NEDGES) return;
    int pos = atomicAdd(&cursor[row[e]], 1);
    cols_s[pos] = col[e];
    vals_s[pos] = val[e];
}

// ---------------------------------------------------------------------------
// gather-only SpMM: one wave per row, lane = dim, register accumulation
// ---------------------------------------------------------------------------
__global__ void spmm_csr_kernel(const int* __restrict__ ptr,
                                const int* __restrict__ cols,
                                const float* __restrict__ vals,
                                const float* __restrict__ x,
                                float* __restrict__ y) {
    int wid  = (blockIdx.x * blockDim.x + threadIdx.x) >> 6;   // wave id = row
    int lane = threadIdx.x & 63;
    if (wid >= NNODES) return;
    int beg = ptr[wid], end = ptr[wid + 1];
    float acc = 0.f;
    int i = beg;
    for (; i + 4 <= end; i += 4) {
        int   c0 = cols[i],     c1 = cols[i + 1], c2 = cols[i + 2], c3 = cols[i + 3];
        float v0 = vals[i],     v1 = vals[i + 1], v2 = vals[i + 2], v3 = vals[i + 3];
        float x0 = x[(size_t)c0 * DIM + lane];
        float x1 = x[(size_t)c1 * DIM + lane];
        float x2 = x[(size_t)c2 * DIM + lane];
        float x3 = x[(size_t)c3 * DIM + lane];
        acc += v0 * x0; acc += v1 * x1; acc += v2 * x2; acc += v3 * x3;
    }
    for (; i < end; ++i)
        acc += vals[i] * x[(size_t)cols[i] * DIM + lane];
    y[(size_t)wid * DIM + lane] = acc;
}

// ---------------------------------------------------------------------------
// fallback atomic SpMM (only if ws_size too small)
// ---------------------------------------------------------------------------
__global__ void spmm_atomic_kernel(const int* __restrict__ row,
                                   const int* __restrict__ col,
                                   const float* __restrict__ val,
                                   const float* __restrict__ x,
                                   float* __restrict__ y) {
    long long tid = (long long)blockIdx.x * blockDim.x + threadIdx.x;
    if (tid >= (long long)NEDGES * 16) return;
    int e = (int)(tid >> 4);
    int q = (int)(tid & 15);
    int r = row[e], c = col[e];
    float v = val[e];
    float4 xv = ((const float4*)x)[(size_t)c * 16 + q];
    float* yp = y + (size_t)r * 64 + q * 4;
    atomicAdd(yp + 0, v * xv.x);
    atomicAdd(yp + 1, v * xv.y);
    atomicAdd(yp + 2, v * xv.z);
    atomicAdd(yp + 3, v * xv.w);
}

// ---------------------------------------------------------------------------
// finalize: mean over the 4 embeddings, split users/items
// ---------------------------------------------------------------------------
__global__ void finalize_kernel(const float4* __restrict__ e0,
                                const float4* __restrict__ e1,
                                const float4* __restrict__ e2,
                                const float4* __restrict__ e3,
                                float4* __restrict__ users,
                                float4* __restrict__ items) {
    int i = blockIdx.x * blockDim.x + threadIdx.x;
    const int tot4 = NNODES * (DIM / 4);
    if (i >= tot4) return;
    float4 a = e0[i], b = e1[i], c = e2[i], d = e3[i];
    float4 m;
    m.x = (a.x + b.x + c.x + d.x) * 0.25f;
    m.y = (a.y + b.y + c.y + d.y) * 0.25f;
    m.z = (a.z + b.z + c.z + d.z) * 0.25f;
    m.w = (a.w + b.w + c.w + d.w) * 0.25f;
    const int nu4 = NUSERS * (DIM / 4);
    if (i < nu4) users[i] = m;
    else         items[i - nu4] = m;
}

extern "C" void kernel_launch(void* const* d_in, const int* in_sizes, int n_in,
                              void* d_out, int out_size, void* d_ws, size_t ws_size,
                              hipStream_t stream) {
    const float* user_emb = (const float*)d_in[0];
    const float* item_emb = (const float*)d_in[1];
    const int*   adj_row  = (const int*)d_in[2];
    const int*   adj_col  = (const int*)d_in[3];
    const float* adj_val  = (const float*)d_in[4];

    float* out   = (float*)d_out;
    float* users = out;
    float* items = out + (size_t)NUSERS * DIM;
    float* e0    = out + (size_t)NNODES * DIM;
    float* e1    = e0 + (size_t)NNODES * DIM;
    float* e2    = e1 + (size_t)NNODES * DIM;
    float* e3    = e2 + (size_t)NNODES * DIM;

    const int tot4 = NNODES * (DIM / 4);
    const int cblk = 256;
    const int cgrid = (tot4 + cblk - 1) / cblk;

    concat_kernel<<<cgrid, cblk, 0, stream>>>(
        (const float4*)user_emb, (const float4*)item_emb, (float4*)e0);

    // workspace layout
    char* ws = (char*)d_ws;
    size_t off = 0;
    auto alloc = [&](size_t bytes) { char* p = ws + off; off += (bytes + 255) & ~(size_t)255; return p; };
    int*   ptr       = (int*)  alloc((NNODES + 1) * sizeof(int));
    int*   cursor    = (int*)  alloc((NNODES + 1) * sizeof(int));
    int*   blockSums = (int*)  alloc(512 * sizeof(int));
    int*   cols_s    = (int*)  alloc((size_t)NEDGES * sizeof(int));
    float* vals_s    = (float*)alloc((size_t)NEDGES * sizeof(float));
    bool have_ws = (off <= ws_size);

    const int eblk = 256;
    const int egrid = (NEDGES + eblk - 1) / eblk;

    if (have_ws) {
        // CSR build (uses `cursor` as the count array first)
        hipMemsetAsync(cursor, 0, (NNODES + 1) * sizeof(int), stream);
        hist_kernel<<<egrid, eblk, 0, stream>>>(adj_row, cursor);
        scan1_kernel<<<NBLK1, SCAN_BLK, 0, stream>>>(cursor, ptr, blockSums);
        scan2_kernel<<<1, 512, 0, stream>>>(blockSums);
        scan3_kernel<<<NBLK1, SCAN_BLK, 0, stream>>>(ptr, cursor, blockSums);
        scatter_kernel<<<egrid, eblk, 0, stream>>>(adj_row, adj_col, adj_val,
                                                   cursor, cols_s, vals_s);

        // gather-only SpMM, one wave per row
        const int sblk = 256;                        // 4 waves/block
        const int sgrid = (NNODES + 3) / 4;          // 75000 blocks
        spmm_csr_kernel<<<sgrid, sblk, 0, stream>>>(ptr, cols_s, vals_s, e0, e1);
        spmm_csr_kernel<<<sgrid, sblk, 0, stream>>>(ptr, cols_s, vals_s, e1, e2);
        spmm_csr_kernel<<<sgrid, sblk, 0, stream>>>(ptr, cols_s, vals_s, e2, e3);
    } else {
        // fallback: atomic scatter path
        hipMemsetAsync(e1, 0, (size_t)3 * NNODES * DIM * sizeof(float), stream);
        const long long st = (long long)NEDGES * 16;
        const int sgrid = (int)((st + 255) / 256);
        spmm_atomic_kernel<<<sgrid, 256, 0, stream>>>(adj_row, adj_col, adj_val, e0, e1);
        spmm_atomic_kernel<<<sgrid, 256, 0, stream>>>(adj_row, adj_col, adj_val, e1, e2);
        spmm_atomic_kernel<<<sgrid, 256, 0, stream>>>(adj_row, adj_col, adj_val, e2, e3);
    }

    finalize_kernel<<<cgrid, cblk, 0, stream>>>(
        (const float4*)e0, (const float4*)e1, (const float4*)e2, (const float4*)e3,
        (float4*)users, (float4*)items);
}